// Round 1
// 815.775 us; speedup vs baseline: 1.2913x; 1.2913x over previous
//
#include <hip/hip_runtime.h>
#include <stdint.h>

// ---------------------------------------------------------------------------
// SemanticMemoryModule: out = softmax((H@Wp + bp) @ C^T) @ C @ Wo + bo
// fp32 operands -> bf16 hi/lo planes; 3 cross terms folded into one K=6144
// GEMM via block-uniform k remaps:
//   A planes [Xh,Xh,Xl]: kA = k<2048 ? k : k-2048   (layout [Xh|Xl], lda 4096)
//   B planes [Yh,Yl,Yh]: kB = k<4096 ? k : k-4096   (layout [Yh|Yl], ldb 4096)
//
// R6 occupancy round: scores GEMM was 1 block/CU (grid 256, Occ 10.8%,
// MfmaUtil 17%) + 16-way LDS read conflict (1.9e7 cyc/dispatch).
//  - H2 (full 16384x4096 bf16, 128MB) now lives in d_out itself: H2 row r ==
//    out row r bytes; scores GEMM of chunk c reads them before the final GEMM
//    of chunk c overwrites them (stream-ordered). Frees ws -> cr=8192
//    (ws 44.07MB, known fits; cr=16384 if ws >= 76.1MB).
//  - scores GEMM: BN=64 tiles -> grid (cr/128,16) = 1024 blocks = 4/CU.
//  - out GEMM: BN=128, grid (cr/128,16) = 1024 = 4/CU at cr=8192.
//  - LDS XOR swizzle (chunk ^= row&7) on both ds_write and ds_read sides.
//  - prepass GEMMs: BN=64 + split-K=4 (fp32 partials in d_out[40,72MB) +
//    reduce kernels) -> 1024 blocks (were 128 = half GPU idle).
//  - sb bias folded into softmax (same fp32 math).
// ws: CWT 4MB | sb 64KB | WpC2 8MB | sp cr*4KB.
// ---------------------------------------------------------------------------

typedef unsigned short ushort_t;
typedef __bf16 bf16x8  __attribute__((ext_vector_type(8)));
typedef short  shortx8 __attribute__((ext_vector_type(8)));
typedef short  shortx4 __attribute__((ext_vector_type(4)));
typedef float  floatx4 __attribute__((ext_vector_type(4)));

__device__ __forceinline__ float bf2f(ushort_t u) {
  union { unsigned u; float f; } x; x.u = ((unsigned)u) << 16; return x.f;
}
__device__ __forceinline__ ushort_t f2bf(float f) {
  union { float f; unsigned u; } x; x.f = f;
  unsigned r = x.u + 0x7FFFu + ((x.u >> 16) & 1u);   // RNE
  return (ushort_t)(r >> 16);
}

// ---------------------------------------------------------------------------
// out[M,N] = A[M,K] (x) Bt[N,K]^T, 128xBN tile, BK=64, 4 waves, bf16 MFMA.
// fp32 out (+ optional bias[col]); split-K via blockIdx.z (k range
// [z*Kslice, min(+Kslice,K)), out plane at outp + z*zstride).
// Block-uniform k remaps: kA = k<athr ? k : k-asub; kB likewise.
// LDS XOR swizzle: 16B chunk index ^= (row&7) on write and read (kills the
// 16-way same-column bank conflict of the 128B-stride row-major tile).
// ---------------------------------------------------------------------------
template<int BN>
__global__ __launch_bounds__(256) void gemm_bt(
    const ushort_t* __restrict__ A, const ushort_t* __restrict__ Bt,
    float* __restrict__ outp, const float* __restrict__ biasp,
    int K, int Kslice, int lda, int ldb, int ldo, size_t zstride,
    int Mvalid, int Nvalid, int athr, int asub, int bthr, int bsub)
{
  constexpr int NJ    = BN / 32;   // 16-col acc tiles per wave
  constexpr int BSTEP = BN / 32;   // B staging passes (32 rows each)
  __shared__ __align__(16) ushort_t As[128 * 64];
  __shared__ __align__(16) ushort_t Bs[BN * 64];

  const int tid  = threadIdx.x;
  const int wave = tid >> 6;
  const int lane = tid & 63;
  const int m0 = blockIdx.x * 128;
  const int n0 = blockIdx.y * BN;

  const int kbeg = blockIdx.z * Kslice;
  const int kend = min(kbeg + Kslice, K);
  float* __restrict__ out = outp + (size_t)blockIdx.z * zstride;

  const int rg = tid >> 3;            // staging row in 32-row group
  const int ck = (tid & 7) * 8;       // staging k-chunk (16B)
  const int swc = (rg & 7) << 3;      // write-side swizzle (row&7: 32|8)

  floatx4 acc[4][NJ] = {};
  const int wm = (wave >> 1) * 64;
  const int wn = (wave & 1) * (BN / 2);
  const int fr = lane & 15;
  const int fq = lane >> 4;
  const int sw = (fr & 7) << 3;       // read-side swizzle (row&7 == fr&7)

  shortx8 ra[4], rb[BSTEP];
  {
    int ka0 = (kbeg < athr) ? kbeg : kbeg - asub;
    int kb0 = (kbeg < bthr) ? kbeg : kbeg - bsub;
#pragma unroll
    for (int s = 0; s < 4; ++s) {
      int mg = min(m0 + s * 32 + rg, Mvalid - 1);
      ra[s] = *(const shortx8*)&A[(size_t)mg * lda + ka0 + ck];
    }
#pragma unroll
    for (int s = 0; s < BSTEP; ++s) {
      int ng = min(n0 + s * 32 + rg, Nvalid - 1);
      rb[s] = *(const shortx8*)&Bt[(size_t)ng * ldb + kb0 + ck];
    }
  }

  for (int k0 = kbeg; k0 < kend; k0 += 64) {
    __syncthreads();
#pragma unroll
    for (int s = 0; s < 4; ++s)
      *(shortx8*)&As[(s * 32 + rg) * 64 + (ck ^ swc)] = ra[s];
#pragma unroll
    for (int s = 0; s < BSTEP; ++s)
      *(shortx8*)&Bs[(s * 32 + rg) * 64 + (ck ^ swc)] = rb[s];
    __syncthreads();

    int kn = k0 + 64;
    if (kn < kend) {                   // block-uniform remap
      int ka0 = (kn < athr) ? kn : kn - asub;
      int kb0 = (kn < bthr) ? kn : kn - bsub;
#pragma unroll
      for (int s = 0; s < 4; ++s) {
        int mg = min(m0 + s * 32 + rg, Mvalid - 1);
        ra[s] = *(const shortx8*)&A[(size_t)mg * lda + ka0 + ck];
      }
#pragma unroll
      for (int s = 0; s < BSTEP; ++s) {
        int ng = min(n0 + s * 32 + rg, Nvalid - 1);
        rb[s] = *(const shortx8*)&Bt[(size_t)ng * ldb + kb0 + ck];
      }
    }

#pragma unroll
    for (int kk = 0; kk < 2; ++kk) {
      const int cs = (kk * 32 + fq * 8) ^ sw;
      shortx8 a[4], b[NJ];
#pragma unroll
      for (int i = 0; i < 4; ++i)
        a[i] = *(const shortx8*)&As[(wm + i * 16 + fr) * 64 + cs];
#pragma unroll
      for (int j = 0; j < NJ; ++j)
        b[j] = *(const shortx8*)&Bs[(wn + j * 16 + fr) * 64 + cs];
#pragma unroll
      for (int i = 0; i < 4; ++i)
#pragma unroll
        for (int j = 0; j < NJ; ++j)
          acc[i][j] = __builtin_amdgcn_mfma_f32_16x16x32_bf16(
              __builtin_bit_cast(bf16x8, a[i]), __builtin_bit_cast(bf16x8, b[j]),
              acc[i][j], 0, 0, 0);
    }
  }

  // D layout: col = lane&15 (n), row = quad*4 + r (m)   [m89/m91-verified]
#pragma unroll
  for (int i = 0; i < 4; ++i) {
#pragma unroll
    for (int j = 0; j < NJ; ++j) {
      int col = n0 + wn + j * 16 + fr;
      float bb = biasp ? biasp[col] : 0.0f;
#pragma unroll
      for (int r = 0; r < 4; ++r) {
        int row = m0 + wm + i * 16 + fq * 4 + r;
        out[(size_t)row * ldo + col] = acc[i][j][r] + bb;
      }
    }
  }
}

// ---------------------------------------------------------------------------
// fp32 [R,Cn] -> bf16 [R,2Cn] hi|lo planes
__global__ __launch_bounds__(256) void split_hilo(
    const float* __restrict__ in, ushort_t* __restrict__ out, int R, int Cn)
{
  int total4 = R * (Cn >> 2);
  for (int i = blockIdx.x * 256 + threadIdx.x; i < total4; i += gridDim.x * 256) {
    int r = i / (Cn >> 2);
    int j = (i - r * (Cn >> 2)) * 4;
    floatx4 v = *(const floatx4*)&in[(size_t)r * Cn + j];
    shortx4 hi, lo;
#pragma unroll
    for (int t = 0; t < 4; ++t) {
      ushort_t h = f2bf(v[t]);
      hi[t] = (short)h;
      lo[t] = (short)f2bf(v[t] - bf2f(h));
    }
    *(shortx4*)&out[(size_t)r * 2 * Cn + j] = hi;
    *(shortx4*)&out[(size_t)r * 2 * Cn + Cn + j] = lo;
  }
}

// Wo fp32 [2048,2048] -> WoT2 bf16 [2048, 4096] = [Wo^T hi | Wo^T lo]
__global__ __launch_bounds__(256) void transpose_split(
    const float* __restrict__ in, ushort_t* __restrict__ out)
{
  __shared__ float t[32][33];
  int bx = blockIdx.x * 32, by = blockIdx.y * 32;
  int x = threadIdx.x;
  for (int i = threadIdx.y; i < 32; i += 8)
    t[i][x] = in[(size_t)(by + i) * 2048 + bx + x];
  __syncthreads();
  for (int i = threadIdx.y; i < 32; i += 8) {
    float v = t[x][i];                      // Wo[by+x][bx+i]: d=bx+i, e=by+x
    ushort_t h = f2bf(v);
    out[(size_t)(bx + i) * 4096 + (by + x)] = h;
    out[(size_t)(bx + i) * 4096 + 2048 + (by + x)] = f2bf(v - bf2f(h));
  }
}

__global__ __launch_bounds__(256) void build_sb(
    const float* __restrict__ bproj, const float* __restrict__ Cc,
    float* __restrict__ sb)
{
  int c = blockIdx.x;
  int cc = min(c, 999);
  float s = 0.f;
  for (int e = threadIdx.x; e < 2048; e += 256)
    s += bproj[e] * Cc[(size_t)cc * 2048 + e];
#pragma unroll
  for (int o = 32; o > 0; o >>= 1) s += __shfl_down(s, o, 64);
  __shared__ float red[4];
  int wave = threadIdx.x >> 6, lane = threadIdx.x & 63;
  if (lane == 0) red[wave] = s;
  __syncthreads();
  if (threadIdx.x == 0) sb[c] = red[0] + red[1] + red[2] + red[3];
}

// 4 fp32 split-K planes [R,C] -> bf16 hi|lo [R, 2C]   (WpC2 finalize)
__global__ __launch_bounds__(256) void reduce_hilo(
    const float* __restrict__ in, size_t plane, ushort_t* __restrict__ out,
    int R, int C)
{
  int total4 = R * (C >> 2);
  for (int i = blockIdx.x * 256 + threadIdx.x; i < total4; i += gridDim.x * 256) {
    int r = i / (C >> 2);
    int j = (i - r * (C >> 2)) * 4;
    size_t idx = (size_t)r * C + j;
    floatx4 v = *(const floatx4*)&in[idx];
#pragma unroll
    for (int p = 1; p < 4; ++p)
      v += *(const floatx4*)&in[p * plane + idx];
    shortx4 hi, lo;
#pragma unroll
    for (int t = 0; t < 4; ++t) {
      ushort_t h = f2bf(v[t]);
      hi[t] = (short)h;
      lo[t] = (short)f2bf(v[t] - bf2f(h));
    }
    *(shortx4*)&out[(size_t)r * 2 * C + j] = hi;
    *(shortx4*)&out[(size_t)r * 2 * C + C + j] = lo;
  }
}

// 4 fp32 split-K planes -> bf16 (flat)   (CWT finalize)
__global__ __launch_bounds__(256) void reduce_bf16(
    const float* __restrict__ in, size_t plane, ushort_t* __restrict__ out,
    int total)
{
  int total4 = total >> 2;
  for (int i = blockIdx.x * 256 + threadIdx.x; i < total4; i += gridDim.x * 256) {
    size_t j = (size_t)i * 4;
    floatx4 v = *(const floatx4*)&in[j];
#pragma unroll
    for (int p = 1; p < 4; ++p)
      v += *(const floatx4*)&in[p * plane + j];
    shortx4 o;
#pragma unroll
    for (int t = 0; t < 4; ++t) o[t] = (short)f2bf(v[t]);
    *(shortx4*)&out[j] = o;
  }
}

// fp32 scores row [1024] + sb bias -> bf16 probs row in-place (first 2KB).
// NaN-scrub + zero-sum guard retained as diagnostic hardening.
__global__ __launch_bounds__(256) void softmax_k(
    void* buf, const float* __restrict__ sb)
{
  int row = blockIdx.x;
  const float* s = (const float*)buf + (size_t)row * 1024;
  ushort_t*    p = (ushort_t*)buf + (size_t)row * 2048;
  int t = threadIdx.x;
  float v[4];
#pragma unroll
  for (int i = 0; i < 4; ++i) {
    int c = t + i * 256;
    float x = (c < 1000) ? s[c] + sb[c] : -3.0e38f;
    v[i] = (x == x) ? x : -3.0e38f;
  }
  float m = fmaxf(fmaxf(v[0], v[1]), fmaxf(v[2], v[3]));
#pragma unroll
  for (int o = 32; o > 0; o >>= 1) m = fmaxf(m, __shfl_xor(m, o, 64));
  __shared__ float redm[4], reds[4];
  int wave = t >> 6, lane = t & 63;
  if (lane == 0) redm[wave] = m;
  __syncthreads();
  m = fmaxf(fmaxf(redm[0], redm[1]), fmaxf(redm[2], redm[3]));
  float pv[4]; float sum = 0.f;
#pragma unroll
  for (int i = 0; i < 4; ++i) {
    int c = t + i * 256;
    pv[i] = (c < 1000) ? __expf(v[i] - m) : 0.f;
    sum += pv[i];
  }
#pragma unroll
  for (int o = 32; o > 0; o >>= 1) sum += __shfl_xor(sum, o, 64);
  if (lane == 0) reds[wave] = sum;
  __syncthreads();
  sum = reds[0] + reds[1] + reds[2] + reds[3];
  float inv = (sum > 0.f) ? 1.0f / sum : 0.f;
#pragma unroll
  for (int i = 0; i < 4; ++i) {
    int c = t + i * 256;
    p[c] = f2bf(pv[i] * inv);
  }
}

// ---------------------------------------------------------------------------
extern "C" void kernel_launch(void* const* d_in, const int* in_sizes, int n_in,
                              void* d_out, int out_size, void* d_ws, size_t ws_size,
                              hipStream_t stream)
{
  const float* H   = (const float*)d_in[0];  // [16384, 2048] fp32
  const float* Cc  = (const float*)d_in[1];  // [1000, 2048]  fp32
  const float* Wp  = (const float*)d_in[2];  // [2048, 2048]  fp32
  const float* bpj = (const float*)d_in[3];  // [2048]        fp32
  const float* Wo  = (const float*)d_in[4];  // [2048, 2048]  fp32
  const float* bo  = (const float*)d_in[5];  // [2048]        fp32
  float* out = (float*)d_out;                // [16384, 2048] fp32 (128MB)

  const size_t MB = (size_t)1 << 20;
  char* ws = (char*)d_ws;

  // persistent ws: CWT 4MB | sb 64KB | WpC2 8MB | sp (scores, cr*4KB)
  ushort_t* CWT  = (ushort_t*)ws;
  float*    sb   = (float*)(ws + 4 * MB);
  ushort_t* WpC2 = (ushort_t*)(ws + 4 * MB + 65536);
  const size_t base2 = 12 * MB + 65536;

  // chunk rows: largest cr with base2 + cr*4KB <= ws_size (floor 128).
  // ws >= 60.07MB proven on this harness -> cr >= 8192.
  int cr = 128;
  for (int c = 16384; c >= 128; c >>= 1)
    if (ws_size >= base2 + (size_t)c * 4096) { cr = c; break; }
  float* sp = (float*)(ws + base2);          // [cr,1024] fp32 / probs bf16

  // d_out scratch (all consumed before split_hilo(H) overwrites d_out):
  char* ob = (char*)d_out;
  ushort_t* C2   = (ushort_t*)ob;              // [1000 x 4096] bf16, ~7.8MB
  ushort_t* Wp2  = (ushort_t*)(ob + 8 * MB);   // [2048 x 4096] bf16, 16MB
  ushort_t* WoT2 = (ushort_t*)(ob + 24 * MB);  // [2048 x 4096] bf16, 16MB
  float*    pp   = (float*)(ob + 40 * MB);     // split-K partials, 32MB (ends 72MB)

  // --- prepasses ---
  split_hilo<<<dim3(2048), dim3(256), 0, stream>>>(Cc, C2, 1000, 2048);
  split_hilo<<<dim3(4096), dim3(256), 0, stream>>>(Wp, Wp2, 2048, 2048);
  transpose_split<<<dim3(64, 64), dim3(32, 8), 0, stream>>>(Wo, WoT2);
  build_sb<<<dim3(1024), dim3(256), 0, stream>>>(bpj, Cc, sb);
  // WpC2 = C @ Wp^T planes: A=C2(Ch,Ch,Cl), B=Wp2(Wh,Wl,Wh), K=6144,
  // split-K=4 -> 4 fp32 planes [1024,2048] in pp, grid 1024 blocks.
  gemm_bt<64><<<dim3(8, 32, 4), dim3(256), 0, stream>>>(
      C2, Wp2, pp, nullptr, 6144, 1536, 4096, 4096, 2048, (size_t)1024 * 2048,
      1000, 2048, 2048, 2048, 4096, 4096);
  reduce_hilo<<<dim3(2048), dim3(256), 0, stream>>>(
      pp, (size_t)1024 * 2048, WpC2, 1024, 2048);
  // CWT = (C @ Wo)^T: A=WoT2(Th,Th,Tl), B=C2(Ch,Cl,Ch), K=6144, split-K=4.
  gemm_bt<64><<<dim3(16, 16, 4), dim3(256), 0, stream>>>(
      WoT2, C2, pp, nullptr, 6144, 1536, 4096, 4096, 1024, (size_t)2048 * 1024,
      2048, 1000, 2048, 2048, 4096, 4096);
  reduce_bf16<<<dim3(2048), dim3(256), 0, stream>>>(
      pp, (size_t)2048 * 1024, CWT, 2048 * 1024);

  // H2 (full) lives in d_out: H2 row r == out row r bytes (8KB each).
  // Chunk c's scores GEMM reads H2 rows [c*cr,(c+1)*cr) strictly before
  // chunk c's final GEMM overwrites them (stream-ordered).
  split_hilo<<<dim3(8192), dim3(256), 0, stream>>>(H, (ushort_t*)ob, 16384, 2048);

  // --- chunked main loop ---
  const int nc = 16384 / cr;
  for (int c = 0; c < nc; ++c) {
    const ushort_t* H2c = (const ushort_t*)ob + (size_t)c * cr * 4096;
    float* outc = out + (size_t)c * cr * 2048;
    // scores: A=H2(Hh,Hh,Hl), B=WpC2(Wh,Wl,Wh), K=6144, fp32 (bias in softmax)
    // BN=64 -> grid (cr/128)*16 = 1024 blocks @ cr=8192 (4 blocks/CU)
    gemm_bt<64><<<dim3(cr / 128, 16, 1), dim3(256), 0, stream>>>(
        H2c, WpC2, sp, nullptr, 6144, 6144, 4096, 4096, 1024, 0,
        cr, 1024, 2048, 2048, 4096, 4096);
    softmax_k<<<dim3(cr), dim3(256), 0, stream>>>(sp, sb);
    // out: A=probs bf16 (lda 2048 in-place), B=CWT, K=1024, fp32 out + bo
    gemm_bt<128><<<dim3(cr / 128, 16, 1), dim3(256), 0, stream>>>(
        (const ushort_t*)sp, CWT, outc, bo, 1024, 1024, 2048, 1024, 2048, 0,
        cr, 2048, 1 << 30, 0, 1 << 30, 0);
  }
}

// Round 2
// 720.245 us; speedup vs baseline: 1.4625x; 1.1326x over previous
//
#include <hip/hip_runtime.h>
#include <stdint.h>

// ---------------------------------------------------------------------------
// SemanticMemoryModule: out = softmax((H@Wp + bp) @ C^T) @ C @ Wo + bo
// fp32 operands -> bf16 hi/lo planes; 3 cross terms folded into one K=6144
// GEMM via block-uniform k remaps:
//   A planes [Xh,Xh,Xl]: kA = k<2048 ? k : k-2048   (layout [Xh|Xl], lda 4096)
//   B planes [Yh,Yl,Yh]: kB = k<4096 ? k : k-4096   (layout [Yh|Yl], ldb 4096)
//
// R7: scores GEMM back to BN=128 (R6's BN=64 was an occupancy fix that
// halved compute intensity; with cr=16384 the BN=128 grid is (128,8) =
// 1024 blocks = 4/CU already). Wave-tile 64x64 -> 32 MFMA / K-step.
// Everything else identical to R6:
//  - H2 (16384x4096 bf16, 128MB) in d_out; row r == out row r bytes;
//    scores GEMM reads them before the final GEMM overwrites (stream order).
//  - LDS XOR swizzle (16B-chunk ^= row&7) both sides -> 0 bank conflicts.
//  - prepass GEMMs: BN=64 + split-K=4 into d_out[40,72MB) + reduce kernels.
//  - sb bias folded into softmax.
// ws: CWT 4MB | sb 64KB | WpC2 8MB | sp cr*4KB  (cr=16384 -> 76.07MB, fits).
// ---------------------------------------------------------------------------

typedef unsigned short ushort_t;
typedef __bf16 bf16x8  __attribute__((ext_vector_type(8)));
typedef short  shortx8 __attribute__((ext_vector_type(8)));
typedef short  shortx4 __attribute__((ext_vector_type(4)));
typedef float  floatx4 __attribute__((ext_vector_type(4)));

__device__ __forceinline__ float bf2f(ushort_t u) {
  union { unsigned u; float f; } x; x.u = ((unsigned)u) << 16; return x.f;
}
__device__ __forceinline__ ushort_t f2bf(float f) {
  union { float f; unsigned u; } x; x.f = f;
  unsigned r = x.u + 0x7FFFu + ((x.u >> 16) & 1u);   // RNE
  return (ushort_t)(r >> 16);
}

// ---------------------------------------------------------------------------
// out[M,N] = A[M,K] (x) Bt[N,K]^T, 128xBN tile, BK=64, 4 waves, bf16 MFMA.
// fp32 out (+ optional bias[col]); split-K via blockIdx.z (k range
// [z*Kslice, min(+Kslice,K)), out plane at outp + z*zstride).
// Block-uniform k remaps: kA = k<athr ? k : k-asub; kB likewise.
// LDS XOR swizzle: 16B chunk index ^= (row&7) on write and read (kills the
// 16-way same-column bank conflict of the 128B-stride row-major tile).
// ---------------------------------------------------------------------------
template<int BN>
__global__ __launch_bounds__(256) void gemm_bt(
    const ushort_t* __restrict__ A, const ushort_t* __restrict__ Bt,
    float* __restrict__ outp, const float* __restrict__ biasp,
    int K, int Kslice, int lda, int ldb, int ldo, size_t zstride,
    int Mvalid, int Nvalid, int athr, int asub, int bthr, int bsub)
{
  constexpr int NJ    = BN / 32;   // 16-col acc tiles per wave
  constexpr int BSTEP = BN / 32;   // B staging passes (32 rows each)
  __shared__ __align__(16) ushort_t As[128 * 64];
  __shared__ __align__(16) ushort_t Bs[BN * 64];

  const int tid  = threadIdx.x;
  const int wave = tid >> 6;
  const int lane = tid & 63;
  const int m0 = blockIdx.x * 128;
  const int n0 = blockIdx.y * BN;

  const int kbeg = blockIdx.z * Kslice;
  const int kend = min(kbeg + Kslice, K);
  float* __restrict__ out = outp + (size_t)blockIdx.z * zstride;

  const int rg = tid >> 3;            // staging row in 32-row group
  const int ck = (tid & 7) * 8;       // staging k-chunk (16B)
  const int swc = (rg & 7) << 3;      // write-side swizzle (row&7: 32|8)

  floatx4 acc[4][NJ] = {};
  const int wm = (wave >> 1) * 64;
  const int wn = (wave & 1) * (BN / 2);
  const int fr = lane & 15;
  const int fq = lane >> 4;
  const int sw = (fr & 7) << 3;       // read-side swizzle (row&7 == fr&7)

  shortx8 ra[4], rb[BSTEP];
  {
    int ka0 = (kbeg < athr) ? kbeg : kbeg - asub;
    int kb0 = (kbeg < bthr) ? kbeg : kbeg - bsub;
#pragma unroll
    for (int s = 0; s < 4; ++s) {
      int mg = min(m0 + s * 32 + rg, Mvalid - 1);
      ra[s] = *(const shortx8*)&A[(size_t)mg * lda + ka0 + ck];
    }
#pragma unroll
    for (int s = 0; s < BSTEP; ++s) {
      int ng = min(n0 + s * 32 + rg, Nvalid - 1);
      rb[s] = *(const shortx8*)&Bt[(size_t)ng * ldb + kb0 + ck];
    }
  }

  for (int k0 = kbeg; k0 < kend; k0 += 64) {
    __syncthreads();
#pragma unroll
    for (int s = 0; s < 4; ++s)
      *(shortx8*)&As[(s * 32 + rg) * 64 + (ck ^ swc)] = ra[s];
#pragma unroll
    for (int s = 0; s < BSTEP; ++s)
      *(shortx8*)&Bs[(s * 32 + rg) * 64 + (ck ^ swc)] = rb[s];
    __syncthreads();

    int kn = k0 + 64;
    if (kn < kend) {                   // block-uniform remap
      int ka0 = (kn < athr) ? kn : kn - asub;
      int kb0 = (kn < bthr) ? kn : kn - bsub;
#pragma unroll
      for (int s = 0; s < 4; ++s) {
        int mg = min(m0 + s * 32 + rg, Mvalid - 1);
        ra[s] = *(const shortx8*)&A[(size_t)mg * lda + ka0 + ck];
      }
#pragma unroll
      for (int s = 0; s < BSTEP; ++s) {
        int ng = min(n0 + s * 32 + rg, Nvalid - 1);
        rb[s] = *(const shortx8*)&Bt[(size_t)ng * ldb + kb0 + ck];
      }
    }

#pragma unroll
    for (int kk = 0; kk < 2; ++kk) {
      const int cs = (kk * 32 + fq * 8) ^ sw;
      shortx8 a[4], b[NJ];
#pragma unroll
      for (int i = 0; i < 4; ++i)
        a[i] = *(const shortx8*)&As[(wm + i * 16 + fr) * 64 + cs];
#pragma unroll
      for (int j = 0; j < NJ; ++j)
        b[j] = *(const shortx8*)&Bs[(wn + j * 16 + fr) * 64 + cs];
#pragma unroll
      for (int i = 0; i < 4; ++i)
#pragma unroll
        for (int j = 0; j < NJ; ++j)
          acc[i][j] = __builtin_amdgcn_mfma_f32_16x16x32_bf16(
              __builtin_bit_cast(bf16x8, a[i]), __builtin_bit_cast(bf16x8, b[j]),
              acc[i][j], 0, 0, 0);
    }
  }

  // D layout: col = lane&15 (n), row = quad*4 + r (m)   [m89/m91-verified]
#pragma unroll
  for (int i = 0; i < 4; ++i) {
#pragma unroll
    for (int j = 0; j < NJ; ++j) {
      int col = n0 + wn + j * 16 + fr;
      float bb = biasp ? biasp[col] : 0.0f;
#pragma unroll
      for (int r = 0; r < 4; ++r) {
        int row = m0 + wm + i * 16 + fq * 4 + r;
        out[(size_t)row * ldo + col] = acc[i][j][r] + bb;
      }
    }
  }
}

// ---------------------------------------------------------------------------
// fp32 [R,Cn] -> bf16 [R,2Cn] hi|lo planes
__global__ __launch_bounds__(256) void split_hilo(
    const float* __restrict__ in, ushort_t* __restrict__ out, int R, int Cn)
{
  int total4 = R * (Cn >> 2);
  for (int i = blockIdx.x * 256 + threadIdx.x; i < total4; i += gridDim.x * 256) {
    int r = i / (Cn >> 2);
    int j = (i - r * (Cn >> 2)) * 4;
    floatx4 v = *(const floatx4*)&in[(size_t)r * Cn + j];
    shortx4 hi, lo;
#pragma unroll
    for (int t = 0; t < 4; ++t) {
      ushort_t h = f2bf(v[t]);
      hi[t] = (short)h;
      lo[t] = (short)f2bf(v[t] - bf2f(h));
    }
    *(shortx4*)&out[(size_t)r * 2 * Cn + j] = hi;
    *(shortx4*)&out[(size_t)r * 2 * Cn + Cn + j] = lo;
  }
}

// Wo fp32 [2048,2048] -> WoT2 bf16 [2048, 4096] = [Wo^T hi | Wo^T lo]
__global__ __launch_bounds__(256) void transpose_split(
    const float* __restrict__ in, ushort_t* __restrict__ out)
{
  __shared__ float t[32][33];
  int bx = blockIdx.x * 32, by = blockIdx.y * 32;
  int x = threadIdx.x;
  for (int i = threadIdx.y; i < 32; i += 8)
    t[i][x] = in[(size_t)(by + i) * 2048 + bx + x];
  __syncthreads();
  for (int i = threadIdx.y; i < 32; i += 8) {
    float v = t[x][i];                      // Wo[by+x][bx+i]: d=bx+i, e=by+x
    ushort_t h = f2bf(v);
    out[(size_t)(bx + i) * 4096 + (by + x)] = h;
    out[(size_t)(bx + i) * 4096 + 2048 + (by + x)] = f2bf(v - bf2f(h));
  }
}

__global__ __launch_bounds__(256) void build_sb(
    const float* __restrict__ bproj, const float* __restrict__ Cc,
    float* __restrict__ sb)
{
  int c = blockIdx.x;
  int cc = min(c, 999);
  float s = 0.f;
  for (int e = threadIdx.x; e < 2048; e += 256)
    s += bproj[e] * Cc[(size_t)cc * 2048 + e];
#pragma unroll
  for (int o = 32; o > 0; o >>= 1) s += __shfl_down(s, o, 64);
  __shared__ float red[4];
  int wave = threadIdx.x >> 6, lane = threadIdx.x & 63;
  if (lane == 0) red[wave] = s;
  __syncthreads();
  if (threadIdx.x == 0) sb[c] = red[0] + red[1] + red[2] + red[3];
}

// 4 fp32 split-K planes [R,C] -> bf16 hi|lo [R, 2C]   (WpC2 finalize)
__global__ __launch_bounds__(256) void reduce_hilo(
    const float* __restrict__ in, size_t plane, ushort_t* __restrict__ out,
    int R, int C)
{
  int total4 = R * (C >> 2);
  for (int i = blockIdx.x * 256 + threadIdx.x; i < total4; i += gridDim.x * 256) {
    int r = i / (C >> 2);
    int j = (i - r * (C >> 2)) * 4;
    size_t idx = (size_t)r * C + j;
    floatx4 v = *(const floatx4*)&in[idx];
#pragma unroll
    for (int p = 1; p < 4; ++p)
      v += *(const floatx4*)&in[p * plane + idx];
    shortx4 hi, lo;
#pragma unroll
    for (int t = 0; t < 4; ++t) {
      ushort_t h = f2bf(v[t]);
      hi[t] = (short)h;
      lo[t] = (short)f2bf(v[t] - bf2f(h));
    }
    *(shortx4*)&out[(size_t)r * 2 * C + j] = hi;
    *(shortx4*)&out[(size_t)r * 2 * C + C + j] = lo;
  }
}

// 4 fp32 split-K planes -> bf16 (flat)   (CWT finalize)
__global__ __launch_bounds__(256) void reduce_bf16(
    const float* __restrict__ in, size_t plane, ushort_t* __restrict__ out,
    int total)
{
  int total4 = total >> 2;
  for (int i = blockIdx.x * 256 + threadIdx.x; i < total4; i += gridDim.x * 256) {
    size_t j = (size_t)i * 4;
    floatx4 v = *(const floatx4*)&in[j];
#pragma unroll
    for (int p = 1; p < 4; ++p)
      v += *(const floatx4*)&in[p * plane + j];
    shortx4 o;
#pragma unroll
    for (int t = 0; t < 4; ++t) o[t] = (short)f2bf(v[t]);
    *(shortx4*)&out[j] = o;
  }
}

// fp32 scores row [1024] + sb bias -> bf16 probs row in-place (first 2KB).
// NaN-scrub + zero-sum guard retained as diagnostic hardening.
__global__ __launch_bounds__(256) void softmax_k(
    void* buf, const float* __restrict__ sb)
{
  int row = blockIdx.x;
  const float* s = (const float*)buf + (size_t)row * 1024;
  ushort_t*    p = (ushort_t*)buf + (size_t)row * 2048;
  int t = threadIdx.x;
  float v[4];
#pragma unroll
  for (int i = 0; i < 4; ++i) {
    int c = t + i * 256;
    float x = (c < 1000) ? s[c] + sb[c] : -3.0e38f;
    v[i] = (x == x) ? x : -3.0e38f;
  }
  float m = fmaxf(fmaxf(v[0], v[1]), fmaxf(v[2], v[3]));
#pragma unroll
  for (int o = 32; o > 0; o >>= 1) m = fmaxf(m, __shfl_xor(m, o, 64));
  __shared__ float redm[4], reds[4];
  int wave = t >> 6, lane = t & 63;
  if (lane == 0) redm[wave] = m;
  __syncthreads();
  m = fmaxf(fmaxf(redm[0], redm[1]), fmaxf(redm[2], redm[3]));
  float pv[4]; float sum = 0.f;
#pragma unroll
  for (int i = 0; i < 4; ++i) {
    int c = t + i * 256;
    pv[i] = (c < 1000) ? __expf(v[i] - m) : 0.f;
    sum += pv[i];
  }
#pragma unroll
  for (int o = 32; o > 0; o >>= 1) sum += __shfl_xor(sum, o, 64);
  if (lane == 0) reds[wave] = sum;
  __syncthreads();
  sum = reds[0] + reds[1] + reds[2] + reds[3];
  float inv = (sum > 0.f) ? 1.0f / sum : 0.f;
#pragma unroll
  for (int i = 0; i < 4; ++i) {
    int c = t + i * 256;
    p[c] = f2bf(pv[i] * inv);
  }
}

// ---------------------------------------------------------------------------
extern "C" void kernel_launch(void* const* d_in, const int* in_sizes, int n_in,
                              void* d_out, int out_size, void* d_ws, size_t ws_size,
                              hipStream_t stream)
{
  const float* H   = (const float*)d_in[0];  // [16384, 2048] fp32
  const float* Cc  = (const float*)d_in[1];  // [1000, 2048]  fp32
  const float* Wp  = (const float*)d_in[2];  // [2048, 2048]  fp32
  const float* bpj = (const float*)d_in[3];  // [2048]        fp32
  const float* Wo  = (const float*)d_in[4];  // [2048, 2048]  fp32
  const float* bo  = (const float*)d_in[5];  // [2048]        fp32
  float* out = (float*)d_out;                // [16384, 2048] fp32 (128MB)

  const size_t MB = (size_t)1 << 20;
  char* ws = (char*)d_ws;

  // persistent ws: CWT 4MB | sb 64KB | WpC2 8MB | sp (scores, cr*4KB)
  ushort_t* CWT  = (ushort_t*)ws;
  float*    sb   = (float*)(ws + 4 * MB);
  ushort_t* WpC2 = (ushort_t*)(ws + 4 * MB + 65536);
  const size_t base2 = 12 * MB + 65536;

  // chunk rows: largest cr with base2 + cr*4KB <= ws_size (floor 128).
  int cr = 128;
  for (int c = 16384; c >= 128; c >>= 1)
    if (ws_size >= base2 + (size_t)c * 4096) { cr = c; break; }
  float* sp = (float*)(ws + base2);          // [cr,1024] fp32 / probs bf16

  // d_out scratch (all consumed before split_hilo(H) overwrites d_out):
  char* ob = (char*)d_out;
  ushort_t* C2   = (ushort_t*)ob;              // [1000 x 4096] bf16, ~7.8MB
  ushort_t* Wp2  = (ushort_t*)(ob + 8 * MB);   // [2048 x 4096] bf16, 16MB
  ushort_t* WoT2 = (ushort_t*)(ob + 24 * MB);  // [2048 x 4096] bf16, 16MB
  float*    pp   = (float*)(ob + 40 * MB);     // split-K partials, 32MB (ends 72MB)

  // --- prepasses ---
  split_hilo<<<dim3(2048), dim3(256), 0, stream>>>(Cc, C2, 1000, 2048);
  split_hilo<<<dim3(4096), dim3(256), 0, stream>>>(Wp, Wp2, 2048, 2048);
  transpose_split<<<dim3(64, 64), dim3(32, 8), 0, stream>>>(Wo, WoT2);
  build_sb<<<dim3(1024), dim3(256), 0, stream>>>(bpj, Cc, sb);
  // WpC2 = C @ Wp^T planes: A=C2(Ch,Ch,Cl), B=Wp2(Wh,Wl,Wh), K=6144,
  // split-K=4 -> 4 fp32 planes [1024,2048] in pp, grid 1024 blocks.
  gemm_bt<64><<<dim3(8, 32, 4), dim3(256), 0, stream>>>(
      C2, Wp2, pp, nullptr, 6144, 1536, 4096, 4096, 2048, (size_t)1024 * 2048,
      1000, 2048, 2048, 2048, 4096, 4096);
  reduce_hilo<<<dim3(2048), dim3(256), 0, stream>>>(
      pp, (size_t)1024 * 2048, WpC2, 1024, 2048);
  // CWT = (C @ Wo)^T: A=WoT2(Th,Th,Tl), B=C2(Ch,Cl,Ch), K=6144, split-K=4.
  gemm_bt<64><<<dim3(16, 16, 4), dim3(256), 0, stream>>>(
      WoT2, C2, pp, nullptr, 6144, 1536, 4096, 4096, 1024, (size_t)2048 * 1024,
      2048, 1000, 2048, 2048, 4096, 4096);
  reduce_bf16<<<dim3(2048), dim3(256), 0, stream>>>(
      pp, (size_t)2048 * 1024, CWT, 2048 * 1024);

  // H2 (full) lives in d_out: H2 row r == out row r bytes (8KB each).
  // Chunk c's scores GEMM reads H2 rows [c*cr,(c+1)*cr) strictly before
  // chunk c's final GEMM overwrites them (stream-ordered).
  split_hilo<<<dim3(8192), dim3(256), 0, stream>>>(H, (ushort_t*)ob, 16384, 2048);

  // --- chunked main loop ---
  const int nc = 16384 / cr;
  for (int c = 0; c < nc; ++c) {
    const ushort_t* H2c = (const ushort_t*)ob + (size_t)c * cr * 4096;
    float* outc = out + (size_t)c * cr * 2048;
    // scores: A=H2(Hh,Hh,Hl), B=WpC2(Wh,Wl,Wh), K=6144, fp32 (bias in softmax)
    // BN=128 -> grid (cr/128, 8) = 1024 blocks @ cr=16384 (4 blocks/CU)
    gemm_bt<128><<<dim3(cr / 128, 8, 1), dim3(256), 0, stream>>>(
        H2c, WpC2, sp, nullptr, 6144, 6144, 4096, 4096, 1024, 0,
        cr, 1024, 2048, 2048, 4096, 4096);
    softmax_k<<<dim3(cr), dim3(256), 0, stream>>>(sp, sb);
    // out: A=probs bf16 (lda 2048 in-place), B=CWT, K=1024, fp32 out + bo
    gemm_bt<128><<<dim3(cr / 128, 16, 1), dim3(256), 0, stream>>>(
        (const ushort_t*)sp, CWT, outc, bo, 1024, 1024, 2048, 1024, 2048, 0,
        cr, 2048, 1 << 30, 0, 1 << 30, 0);
  }
}

// Round 3
// 653.620 us; speedup vs baseline: 1.6116x; 1.1019x over previous
//
#include <hip/hip_runtime.h>
#include <stdint.h>

// ---------------------------------------------------------------------------
// SemanticMemoryModule: out = softmax((H@Wp + bp) @ C^T) @ C @ Wo + bo
// fp32 operands -> bf16 hi/lo planes; 3 cross terms folded into one K=6144
// GEMM via block-uniform k remaps:
//   A planes [Xh,Xh,Xl]: kA = k<2048 ? k : k-2048   (layout [Xh|Xl], lda 4096)
//   B planes [Yh,Yl,Yh]: kB = k<4096 ? k : k-4096   (layout [Yh|Yl], ldb 4096)
//
// R8: scores + out GEMMs moved to a 256x256 8-wave counted-vmcnt structure
// (T3+T4+T5): R2 showed the 128-tile 2-drain-barrier loop pinned at the m97
// ceiling (MfmaUtil 35%, conflicts 0, HBM 33%).
//  - 512 thr (8 waves, 2Mx4N), BK=64, LDS 128KB = 2 dbuf x (A 32KB + B 32KB).
//  - staging: global_load_lds_dwordx4, LINEAR LDS dest + per-lane
//    inverse-swizzled global source (chunk ^= row&7); reads swizzle same way
//    (proven 0-conflict involution from R1/R2).
//  - raw s_barrier + inline-asm s_waitcnt vmcnt(8) (vmcnt(0) only at last
//    K-step): next tile's 8 stages stay in flight across barriers.
//  - setprio(1) around MFMA clusters.
// Prepasses unchanged (128-tile gemm_bt<64> split-K). H2 in d_out as before.
// ws: CWT 4MB | sb 64KB | WpC2 8MB | sp cr*4KB  (cr=16384 -> 76.07MB, fits).
// ---------------------------------------------------------------------------

typedef unsigned short ushort_t;
typedef __bf16 bf16x8  __attribute__((ext_vector_type(8)));
typedef short  shortx8 __attribute__((ext_vector_type(8)));
typedef short  shortx4 __attribute__((ext_vector_type(4)));
typedef float  floatx4 __attribute__((ext_vector_type(4)));

__device__ __forceinline__ float bf2f(ushort_t u) {
  union { unsigned u; float f; } x; x.u = ((unsigned)u) << 16; return x.f;
}
__device__ __forceinline__ ushort_t f2bf(float f) {
  union { float f; unsigned u; } x; x.f = f;
  unsigned r = x.u + 0x7FFFu + ((x.u >> 16) & 1u);   // RNE
  return (ushort_t)(r >> 16);
}

__device__ __forceinline__ void gll16(const void* g, void* l) {
  __builtin_amdgcn_global_load_lds(
      (const __attribute__((address_space(1))) void*)g,
      (__attribute__((address_space(3))) void*)l, 16, 0, 0);
}

// ---------------------------------------------------------------------------
// 256x256 tile, 8 waves, BK=64, counted-vmcnt double-buffer GEMM.
// out[M,N] = A[M,K] (x) Bt[N,K]^T, fp32 out + optional bias[col].
// Block-uniform k remaps as above.
// ---------------------------------------------------------------------------
__device__ __forceinline__ void stage_tile256(
    const ushort_t* __restrict__ A, const ushort_t* __restrict__ Bt,
    ushort_t* ldsA, ushort_t* ldsB, int wave, int lane,
    int m0, int n0, int lda, int ldb, int Mvalid, int Nvalid, int ka, int kb)
{
  const int rsub = lane >> 3;                 // row within 8-row block
  const int csw  = ((lane & 7) ^ rsub) << 3;  // inverse-swizzled chunk (ushorts)
#pragma unroll
  for (int s = 0; s < 4; ++s) {
    const int q = wave * 4 + s;               // 8-row block index 0..31
    const int r = q * 8 + rsub;
    int gm = min(m0 + r, Mvalid - 1);
    gll16(&A[(size_t)gm * lda + ka + csw], &ldsA[q * 512]);
    int gn = min(n0 + r, Nvalid - 1);
    gll16(&Bt[(size_t)gn * ldb + kb + csw], &ldsB[q * 512]);
  }
}

__global__ __launch_bounds__(512, 2) void gemm256(
    const ushort_t* __restrict__ A, const ushort_t* __restrict__ Bt,
    float* __restrict__ outp, const float* __restrict__ biasp,
    int K, int lda, int ldb, int ldo, int Mvalid, int Nvalid,
    int athr, int asub, int bthr, int bsub)
{
  __shared__ __align__(16) ushort_t lds[65536];   // 128 KB: [2][A 16K|B 16K]

  const int tid  = threadIdx.x;
  const int wave = tid >> 6;
  const int lane = tid & 63;
  const int m0 = blockIdx.x * 256;
  const int n0 = blockIdx.y * 256;
  const int wm = (wave >> 2) * 128;
  const int wn = (wave & 3) * 64;
  const int fr = lane & 15;
  const int fq = lane >> 4;
  const int NT = K >> 6;

  const int cs0 = ((fq    ) ^ (fr & 7)) << 3;  // kk=0 swizzled chunk (ushorts)
  const int cs1 = ((fq + 4) ^ (fr & 7)) << 3;  // kk=1

  // prologue: stage tiles 0 and 1
  {
    int k0a = (0 < athr) ? 0 : -asub;
    stage_tile256(A, Bt, &lds[0], &lds[16384], wave, lane, m0, n0, lda, ldb,
                  Mvalid, Nvalid, 0, 0);
    (void)k0a;
    if (NT > 1) {
      int ka = (64 < athr) ? 64 : 64 - asub;
      int kb = (64 < bthr) ? 64 : 64 - bsub;
      stage_tile256(A, Bt, &lds[32768], &lds[49152], wave, lane, m0, n0,
                    lda, ldb, Mvalid, Nvalid, ka, kb);
    }
  }

  floatx4 acc[8][4] = {};

  for (int t = 0; t < NT; ++t) {
    const int p = t & 1;
    const ushort_t* Ab = &lds[p * 32768];
    const ushort_t* Bb = &lds[p * 32768 + 16384];

    if (t + 1 < NT) { asm volatile("s_waitcnt vmcnt(8)" ::: "memory"); }
    else            { asm volatile("s_waitcnt vmcnt(0)" ::: "memory"); }
    __builtin_amdgcn_s_barrier();

    shortx8 a[8], b[4];
#pragma unroll
    for (int i = 0; i < 8; ++i)
      a[i] = *(const shortx8*)&Ab[(wm + i * 16 + fr) * 64 + cs0];
#pragma unroll
    for (int j = 0; j < 4; ++j)
      b[j] = *(const shortx8*)&Bb[(wn + j * 16 + fr) * 64 + cs0];
    __builtin_amdgcn_s_setprio(1);
#pragma unroll
    for (int i = 0; i < 8; ++i)
#pragma unroll
      for (int j = 0; j < 4; ++j)
        acc[i][j] = __builtin_amdgcn_mfma_f32_16x16x32_bf16(
            __builtin_bit_cast(bf16x8, a[i]), __builtin_bit_cast(bf16x8, b[j]),
            acc[i][j], 0, 0, 0);
    __builtin_amdgcn_s_setprio(0);
#pragma unroll
    for (int i = 0; i < 8; ++i)
      a[i] = *(const shortx8*)&Ab[(wm + i * 16 + fr) * 64 + cs1];
#pragma unroll
    for (int j = 0; j < 4; ++j)
      b[j] = *(const shortx8*)&Bb[(wn + j * 16 + fr) * 64 + cs1];
    __builtin_amdgcn_s_setprio(1);
#pragma unroll
    for (int i = 0; i < 8; ++i)
#pragma unroll
      for (int j = 0; j < 4; ++j)
        acc[i][j] = __builtin_amdgcn_mfma_f32_16x16x32_bf16(
            __builtin_bit_cast(bf16x8, a[i]), __builtin_bit_cast(bf16x8, b[j]),
            acc[i][j], 0, 0, 0);
    __builtin_amdgcn_s_setprio(0);

    __builtin_amdgcn_s_barrier();     // all reads of buf p done

    if (t + 2 < NT) {
      int k2 = (t + 2) << 6;
      int ka = (k2 < athr) ? k2 : k2 - asub;
      int kb = (k2 < bthr) ? k2 : k2 - bsub;
      stage_tile256(A, Bt, &lds[p * 32768], &lds[p * 32768 + 16384],
                    wave, lane, m0, n0, lda, ldb, Mvalid, Nvalid, ka, kb);
    }
  }

  // D layout: col = lane&15 (n), row = quad*4 + r (m)   [m89/m91-verified]
#pragma unroll
  for (int i = 0; i < 8; ++i) {
#pragma unroll
    for (int j = 0; j < 4; ++j) {
      int col = n0 + wn + j * 16 + fr;
      float bb = biasp ? biasp[col] : 0.0f;
#pragma unroll
      for (int r = 0; r < 4; ++r) {
        int row = m0 + wm + i * 16 + fq * 4 + r;
        outp[(size_t)row * ldo + col] = acc[i][j][r] + bb;
      }
    }
  }
}

// ---------------------------------------------------------------------------
// 128xBN reg-staged GEMM (prepass use only now), split-K via blockIdx.z.
// ---------------------------------------------------------------------------
template<int BN>
__global__ __launch_bounds__(256) void gemm_bt(
    const ushort_t* __restrict__ A, const ushort_t* __restrict__ Bt,
    float* __restrict__ outp, const float* __restrict__ biasp,
    int K, int Kslice, int lda, int ldb, int ldo, size_t zstride,
    int Mvalid, int Nvalid, int athr, int asub, int bthr, int bsub)
{
  constexpr int NJ    = BN / 32;
  constexpr int BSTEP = BN / 32;
  __shared__ __align__(16) ushort_t As[128 * 64];
  __shared__ __align__(16) ushort_t Bs[BN * 64];

  const int tid  = threadIdx.x;
  const int wave = tid >> 6;
  const int lane = tid & 63;
  const int m0 = blockIdx.x * 128;
  const int n0 = blockIdx.y * BN;

  const int kbeg = blockIdx.z * Kslice;
  const int kend = min(kbeg + Kslice, K);
  float* __restrict__ out = outp + (size_t)blockIdx.z * zstride;

  const int rg = tid >> 3;
  const int ck = (tid & 7) * 8;
  const int swc = (rg & 7) << 3;

  floatx4 acc[4][NJ] = {};
  const int wm = (wave >> 1) * 64;
  const int wn = (wave & 1) * (BN / 2);
  const int fr = lane & 15;
  const int fq = lane >> 4;
  const int sw = (fr & 7) << 3;

  shortx8 ra[4], rb[BSTEP];
  {
    int ka0 = (kbeg < athr) ? kbeg : kbeg - asub;
    int kb0 = (kbeg < bthr) ? kbeg : kbeg - bsub;
#pragma unroll
    for (int s = 0; s < 4; ++s) {
      int mg = min(m0 + s * 32 + rg, Mvalid - 1);
      ra[s] = *(const shortx8*)&A[(size_t)mg * lda + ka0 + ck];
    }
#pragma unroll
    for (int s = 0; s < BSTEP; ++s) {
      int ng = min(n0 + s * 32 + rg, Nvalid - 1);
      rb[s] = *(const shortx8*)&Bt[(size_t)ng * ldb + kb0 + ck];
    }
  }

  for (int k0 = kbeg; k0 < kend; k0 += 64) {
    __syncthreads();
#pragma unroll
    for (int s = 0; s < 4; ++s)
      *(shortx8*)&As[(s * 32 + rg) * 64 + (ck ^ swc)] = ra[s];
#pragma unroll
    for (int s = 0; s < BSTEP; ++s)
      *(shortx8*)&Bs[(s * 32 + rg) * 64 + (ck ^ swc)] = rb[s];
    __syncthreads();

    int kn = k0 + 64;
    if (kn < kend) {
      int ka0 = (kn < athr) ? kn : kn - asub;
      int kb0 = (kn < bthr) ? kn : kn - bsub;
#pragma unroll
      for (int s = 0; s < 4; ++s) {
        int mg = min(m0 + s * 32 + rg, Mvalid - 1);
        ra[s] = *(const shortx8*)&A[(size_t)mg * lda + ka0 + ck];
      }
#pragma unroll
      for (int s = 0; s < BSTEP; ++s) {
        int ng = min(n0 + s * 32 + rg, Nvalid - 1);
        rb[s] = *(const shortx8*)&Bt[(size_t)ng * ldb + kb0 + ck];
      }
    }

#pragma unroll
    for (int kk = 0; kk < 2; ++kk) {
      const int cs = (kk * 32 + fq * 8) ^ sw;
      shortx8 a[4], b[NJ];
#pragma unroll
      for (int i = 0; i < 4; ++i)
        a[i] = *(const shortx8*)&As[(wm + i * 16 + fr) * 64 + cs];
#pragma unroll
      for (int j = 0; j < NJ; ++j)
        b[j] = *(const shortx8*)&Bs[(wn + j * 16 + fr) * 64 + cs];
#pragma unroll
      for (int i = 0; i < 4; ++i)
#pragma unroll
        for (int j = 0; j < NJ; ++j)
          acc[i][j] = __builtin_amdgcn_mfma_f32_16x16x32_bf16(
              __builtin_bit_cast(bf16x8, a[i]), __builtin_bit_cast(bf16x8, b[j]),
              acc[i][j], 0, 0, 0);
    }
  }

#pragma unroll
  for (int i = 0; i < 4; ++i) {
#pragma unroll
    for (int j = 0; j < NJ; ++j) {
      int col = n0 + wn + j * 16 + fr;
      float bb = biasp ? biasp[col] : 0.0f;
#pragma unroll
      for (int r = 0; r < 4; ++r) {
        int row = m0 + wm + i * 16 + fq * 4 + r;
        out[(size_t)row * ldo + col] = acc[i][j][r] + bb;
      }
    }
  }
}

// ---------------------------------------------------------------------------
// fp32 [R,Cn] -> bf16 [R,2Cn] hi|lo planes
__global__ __launch_bounds__(256) void split_hilo(
    const float* __restrict__ in, ushort_t* __restrict__ out, int R, int Cn)
{
  int total4 = R * (Cn >> 2);
  for (int i = blockIdx.x * 256 + threadIdx.x; i < total4; i += gridDim.x * 256) {
    int r = i / (Cn >> 2);
    int j = (i - r * (Cn >> 2)) * 4;
    floatx4 v = *(const floatx4*)&in[(size_t)r * Cn + j];
    shortx4 hi, lo;
#pragma unroll
    for (int t = 0; t < 4; ++t) {
      ushort_t h = f2bf(v[t]);
      hi[t] = (short)h;
      lo[t] = (short)f2bf(v[t] - bf2f(h));
    }
    *(shortx4*)&out[(size_t)r * 2 * Cn + j] = hi;
    *(shortx4*)&out[(size_t)r * 2 * Cn + Cn + j] = lo;
  }
}

// Wo fp32 [2048,2048] -> WoT2 bf16 [2048, 4096] = [Wo^T hi | Wo^T lo]
__global__ __launch_bounds__(256) void transpose_split(
    const float* __restrict__ in, ushort_t* __restrict__ out)
{
  __shared__ float t[32][33];
  int bx = blockIdx.x * 32, by = blockIdx.y * 32;
  int x = threadIdx.x;
  for (int i = threadIdx.y; i < 32; i += 8)
    t[i][x] = in[(size_t)(by + i) * 2048 + bx + x];
  __syncthreads();
  for (int i = threadIdx.y; i < 32; i += 8) {
    float v = t[x][i];
    ushort_t h = f2bf(v);
    out[(size_t)(bx + i) * 4096 + (by + x)] = h;
    out[(size_t)(bx + i) * 4096 + 2048 + (by + x)] = f2bf(v - bf2f(h));
  }
}

__global__ __launch_bounds__(256) void build_sb(
    const float* __restrict__ bproj, const float* __restrict__ Cc,
    float* __restrict__ sb)
{
  int c = blockIdx.x;
  int cc = min(c, 999);
  float s = 0.f;
  for (int e = threadIdx.x; e < 2048; e += 256)
    s += bproj[e] * Cc[(size_t)cc * 2048 + e];
#pragma unroll
  for (int o = 32; o > 0; o >>= 1) s += __shfl_down(s, o, 64);
  __shared__ float red[4];
  int wave = threadIdx.x >> 6, lane = threadIdx.x & 63;
  if (lane == 0) red[wave] = s;
  __syncthreads();
  if (threadIdx.x == 0) sb[c] = red[0] + red[1] + red[2] + red[3];
}

// 4 fp32 split-K planes [R,C] -> bf16 hi|lo [R, 2C]   (WpC2 finalize)
__global__ __launch_bounds__(256) void reduce_hilo(
    const float* __restrict__ in, size_t plane, ushort_t* __restrict__ out,
    int R, int C)
{
  int total4 = R * (C >> 2);
  for (int i = blockIdx.x * 256 + threadIdx.x; i < total4; i += gridDim.x * 256) {
    int r = i / (C >> 2);
    int j = (i - r * (C >> 2)) * 4;
    size_t idx = (size_t)r * C + j;
    floatx4 v = *(const floatx4*)&in[idx];
#pragma unroll
    for (int p = 1; p < 4; ++p)
      v += *(const floatx4*)&in[p * plane + idx];
    shortx4 hi, lo;
#pragma unroll
    for (int t = 0; t < 4; ++t) {
      ushort_t h = f2bf(v[t]);
      hi[t] = (short)h;
      lo[t] = (short)f2bf(v[t] - bf2f(h));
    }
    *(shortx4*)&out[(size_t)r * 2 * C + j] = hi;
    *(shortx4*)&out[(size_t)r * 2 * C + C + j] = lo;
  }
}

// 4 fp32 split-K planes -> bf16 (flat)   (CWT finalize)
__global__ __launch_bounds__(256) void reduce_bf16(
    const float* __restrict__ in, size_t plane, ushort_t* __restrict__ out,
    int total)
{
  int total4 = total >> 2;
  for (int i = blockIdx.x * 256 + threadIdx.x; i < total4; i += gridDim.x * 256) {
    size_t j = (size_t)i * 4;
    floatx4 v = *(const floatx4*)&in[j];
#pragma unroll
    for (int p = 1; p < 4; ++p)
      v += *(const floatx4*)&in[p * plane + j];
    shortx4 o;
#pragma unroll
    for (int t = 0; t < 4; ++t) o[t] = (short)f2bf(v[t]);
    *(shortx4*)&out[j] = o;
  }
}

// fp32 scores row [1024] + sb bias -> bf16 probs row in-place (first 2KB).
__global__ __launch_bounds__(256) void softmax_k(
    void* buf, const float* __restrict__ sb)
{
  int row = blockIdx.x;
  const float* s = (const float*)buf + (size_t)row * 1024;
  ushort_t*    p = (ushort_t*)buf + (size_t)row * 2048;
  int t = threadIdx.x;
  float v[4];
#pragma unroll
  for (int i = 0; i < 4; ++i) {
    int c = t + i * 256;
    float x = (c < 1000) ? s[c] + sb[c] : -3.0e38f;
    v[i] = (x == x) ? x : -3.0e38f;
  }
  float m = fmaxf(fmaxf(v[0], v[1]), fmaxf(v[2], v[3]));
#pragma unroll
  for (int o = 32; o > 0; o >>= 1) m = fmaxf(m, __shfl_xor(m, o, 64));
  __shared__ float redm[4], reds[4];
  int wave = t >> 6, lane = t & 63;
  if (lane == 0) redm[wave] = m;
  __syncthreads();
  m = fmaxf(fmaxf(redm[0], redm[1]), fmaxf(redm[2], redm[3]));
  float pv[4]; float sum = 0.f;
#pragma unroll
  for (int i = 0; i < 4; ++i) {
    int c = t + i * 256;
    pv[i] = (c < 1000) ? __expf(v[i] - m) : 0.f;
    sum += pv[i];
  }
#pragma unroll
  for (int o = 32; o > 0; o >>= 1) sum += __shfl_xor(sum, o, 64);
  if (lane == 0) reds[wave] = sum;
  __syncthreads();
  sum = reds[0] + reds[1] + reds[2] + reds[3];
  float inv = (sum > 0.f) ? 1.0f / sum : 0.f;
#pragma unroll
  for (int i = 0; i < 4; ++i) {
    int c = t + i * 256;
    p[c] = f2bf(pv[i] * inv);
  }
}

// ---------------------------------------------------------------------------
extern "C" void kernel_launch(void* const* d_in, const int* in_sizes, int n_in,
                              void* d_out, int out_size, void* d_ws, size_t ws_size,
                              hipStream_t stream)
{
  const float* H   = (const float*)d_in[0];  // [16384, 2048] fp32
  const float* Cc  = (const float*)d_in[1];  // [1000, 2048]  fp32
  const float* Wp  = (const float*)d_in[2];  // [2048, 2048]  fp32
  const float* bpj = (const float*)d_in[3];  // [2048]        fp32
  const float* Wo  = (const float*)d_in[4];  // [2048, 2048]  fp32
  const float* bo  = (const float*)d_in[5];  // [2048]        fp32
  float* out = (float*)d_out;                // [16384, 2048] fp32 (128MB)

  const size_t MB = (size_t)1 << 20;
  char* ws = (char*)d_ws;

  // persistent ws: CWT 4MB | sb 64KB | WpC2 8MB | sp (scores, cr*4KB)
  ushort_t* CWT  = (ushort_t*)ws;
  float*    sb   = (float*)(ws + 4 * MB);
  ushort_t* WpC2 = (ushort_t*)(ws + 4 * MB + 65536);
  const size_t base2 = 12 * MB + 65536;

  // chunk rows: largest cr with base2 + cr*4KB <= ws_size (floor 256 for
  // the 256-row tiles of gemm256).
  int cr = 256;
  for (int c = 16384; c >= 256; c >>= 1)
    if (ws_size >= base2 + (size_t)c * 4096) { cr = c; break; }
  float* sp = (float*)(ws + base2);          // [cr,1024] fp32 / probs bf16

  // d_out scratch (all consumed before split_hilo(H) overwrites d_out):
  char* ob = (char*)d_out;
  ushort_t* C2   = (ushort_t*)ob;              // [1000 x 4096] bf16, ~7.8MB
  ushort_t* Wp2  = (ushort_t*)(ob + 8 * MB);   // [2048 x 4096] bf16, 16MB
  ushort_t* WoT2 = (ushort_t*)(ob + 24 * MB);  // [2048 x 4096] bf16, 16MB
  float*    pp   = (float*)(ob + 40 * MB);     // split-K partials, 32MB (ends 72MB)

  // --- prepasses ---
  split_hilo<<<dim3(2048), dim3(256), 0, stream>>>(Cc, C2, 1000, 2048);
  split_hilo<<<dim3(4096), dim3(256), 0, stream>>>(Wp, Wp2, 2048, 2048);
  transpose_split<<<dim3(64, 64), dim3(32, 8), 0, stream>>>(Wo, WoT2);
  build_sb<<<dim3(1024), dim3(256), 0, stream>>>(bpj, Cc, sb);
  // WpC2 = C @ Wp^T planes: split-K=4 -> 4 fp32 planes [1024,2048] in pp.
  gemm_bt<64><<<dim3(8, 32, 4), dim3(256), 0, stream>>>(
      C2, Wp2, pp, nullptr, 6144, 1536, 4096, 4096, 2048, (size_t)1024 * 2048,
      1000, 2048, 2048, 2048, 4096, 4096);
  reduce_hilo<<<dim3(2048), dim3(256), 0, stream>>>(
      pp, (size_t)1024 * 2048, WpC2, 1024, 2048);
  // CWT = (C @ Wo)^T: split-K=4.
  gemm_bt<64><<<dim3(16, 16, 4), dim3(256), 0, stream>>>(
      WoT2, C2, pp, nullptr, 6144, 1536, 4096, 4096, 1024, (size_t)2048 * 1024,
      2048, 1000, 2048, 2048, 4096, 4096);
  reduce_bf16<<<dim3(2048), dim3(256), 0, stream>>>(
      pp, (size_t)2048 * 1024, CWT, 2048 * 1024);

  // H2 (full) lives in d_out: H2 row r == out row r bytes (8KB each).
  split_hilo<<<dim3(8192), dim3(256), 0, stream>>>(H, (ushort_t*)ob, 16384, 2048);

  // --- chunked main loop ---
  const int nc = 16384 / cr;
  for (int c = 0; c < nc; ++c) {
    const ushort_t* H2c = (const ushort_t*)ob + (size_t)c * cr * 4096;
    float* outc = out + (size_t)c * cr * 2048;
    // scores: A=H2(Hh,Hh,Hl), B=WpC2(Wh,Wl,Wh), K=6144, fp32 (bias in softmax)
    // 256x256 tiles -> grid (cr/256, 4) = 256 blocks @ cr=16384 (1/CU, 1 pass)
    gemm256<<<dim3(cr / 256, 4), dim3(512), 0, stream>>>(
        H2c, WpC2, sp, nullptr, 6144, 4096, 4096, 1024,
        cr, 1024, 2048, 2048, 4096, 4096);
    softmax_k<<<dim3(cr), dim3(256), 0, stream>>>(sp, sb);
    // out: A=probs bf16 (lda 2048 in-place), B=CWT, K=1024, fp32 out + bo
    gemm256<<<dim3(cr / 256, 8), dim3(512), 0, stream>>>(
        (const ushort_t*)sp, CWT, outc, bo, 1024, 2048, 1024, 2048,
        cr, 2048, 1 << 30, 0, 1 << 30, 0);
  }
}